// Round 16
// baseline (111.137 us; speedup 1.0000x reference)
//
#include <hip/hip_runtime.h>
#include <hip/hip_bf16.h>

#define S 2048
#define D 1024
#define NH 16
#define DH 64
#define M_TOT 4096  // B*S

typedef float f32x4 __attribute__((ext_vector_type(4)));
typedef float f32x16 __attribute__((ext_vector_type(16)));
typedef __bf16 bf16x8 __attribute__((ext_vector_type(8)));

static __device__ __forceinline__ ushort f2bf(float f) {
    unsigned u = __float_as_uint(f);
    u += 0x7fffu + ((u >> 16) & 1u);   // RNE
    return (ushort)(u >> 16);
}

static __device__ __forceinline__ int cvtpk_bf16(float lo, float hi) {
    int r;
    asm("v_cvt_pk_bf16_f32 %0, %1, %2" : "=v"(r) : "v"(lo), "v"(hi));
    return r;
}

static __device__ __forceinline__ void plswap(int& a, int& b) {
    asm("v_permlane32_swap_b32 %0, %1" : "+v"(a), "+v"(b));
}

static __device__ __forceinline__ float xhalf_add(float x) {
    return x + __shfl_xor(x, 32);
}

// bare hardware exp2 (skips __ocml_exp2_f32's denormal fixup)
static __device__ __forceinline__ float fexp2(float x) {
    float r;
    asm("v_exp_f32 %0, %1" : "=v"(r) : "v"(x));
    return r;
}

static __device__ __forceinline__ void gload16(const ushort* g, ushort* l) {
    __builtin_amdgcn_global_load_lds(
        (const __attribute__((address_space(1))) void*)g,
        (__attribute__((address_space(3))) void*)l, 16, 0, 0);
}

// counted vmcnt wait (T4)
template<int N> static __device__ __forceinline__ void waitvm() {
    if constexpr (N == 0) asm volatile("s_waitcnt vmcnt(0)" ::: "memory");
    else if constexpr (N == 2) asm volatile("s_waitcnt vmcnt(2)" ::: "memory");
    else if constexpr (N == 3) asm volatile("s_waitcnt vmcnt(3)" ::: "memory");
    else if constexpr (N == 4) asm volatile("s_waitcnt vmcnt(4)" ::: "memory");
}
static __device__ __forceinline__ void waitlgkm0() {
    asm volatile("s_waitcnt lgkmcnt(0)" ::: "memory");
}
static __device__ __forceinline__ void rawbar() {
    __builtin_amdgcn_s_barrier();
    __builtin_amdgcn_sched_barrier(0);
}

// ---------------- fused prep: X->bf16 convert + all weight transposes ----------
__global__ void k_prep(const float* __restrict__ X, const float* __restrict__ Wq,
                       const float* __restrict__ Wk, const float* __restrict__ Wv,
                       const float* __restrict__ Wo,
                       ushort* __restrict__ Xb, ushort* __restrict__ Wqkvt,
                       ushort* __restrict__ Wot, float scale0) {
    int z = blockIdx.z;
    int tid = threadIdx.x;
    if (z >= 4) {
        int idx = (((z - 4) * 1024) + blockIdx.y * 32 + blockIdx.x) * 256 + tid;
        float4 v = ((const float4*)X)[idx];
        ushort4 o;
        o.x = f2bf(v.x); o.y = f2bf(v.y); o.z = f2bf(v.z); o.w = f2bf(v.w);
        ((ushort4*)Xb)[idx] = o;
        return;
    }
    __shared__ float tile[32][33];
    const float* src = (z == 0) ? Wq : (z == 1) ? Wk : (z == 2) ? Wv : Wo;
    ushort* dst = (z < 3) ? (Wqkvt + (size_t)z * 1024 * D) : Wot;
    float scl = (z == 0) ? scale0 : 1.0f;
    int bn = blockIdx.x * 32;
    int bk = blockIdx.y * 32;
    int tx = tid & 31, ty = tid >> 5;
    #pragma unroll
    for (int i = 0; i < 32; i += 8)
        tile[ty + i][tx] = src[(size_t)(bk + ty + i) * D + bn + tx];
    __syncthreads();
    #pragma unroll
    for (int i = 0; i < 32; i += 8)
        dst[(size_t)(bn + ty + i) * D + bk + tx] = f2bf(tile[tx][ty + i] * scl);
}

// ---------------- GEMM TN, 3-buffer / 1-barrier counted-vmcnt pipeline ----------
// MF: BM = MF*32.  NF: BN = NF*32.  mode 0 (QKV scatter) requires (MF=2,NF=4).
template<int MF, int NF>
__global__ __launch_bounds__(256) void k_gemm(
    const ushort* __restrict__ A, const ushort* __restrict__ Bt,
    ushort* __restrict__ Qd, ushort* __restrict__ Kd, ushort* __restrict__ Vd,
    float* __restrict__ Od, const float* __restrict__ bias, int mode)
{
    constexpr int BM = MF * 32;
    constexpr int BN = NF * 32;
    constexpr int ASZ = BM * 32;
    constexpr int BSZ = BN * 32;
    constexpr int NL = ((MF == 4) ? 2 : 1) + ((NF == 4) ? 2 : 1);
    __shared__ ushort SH[3 * ASZ + 3 * BSZ];
    ushort* As = SH;
    ushort* Bs = SH + 3 * ASZ;

    int tid = threadIdx.x, wave = tid >> 6, lane = tid & 63;
    int wm = (wave >> 1) * (MF * 16), wn = (wave & 1) * (NF * 16);
    int bm = blockIdx.x * BM, bn0 = blockIdx.y * BN;
    int lr = lane & 15, lk = (lane >> 4) * 8;
    int rr = (lane >> 4) * 4;
    f32x4 acc[MF][NF] = {};

    const ushort* Ap0 = A + (size_t)(bm + (tid >> 2)) * D + (tid & 3) * 8;
    const ushort* Ap1 = A + (size_t)(bm + ((tid + 256) >> 2)) * D + (tid & 3) * 8;
    const ushort* Bp0 = Bt + (size_t)(bn0 + (tid >> 2)) * D + (tid & 3) * 8;
    const ushort* Bp1 = Bt + (size_t)(bn0 + ((tid + 256) >> 2)) * D + (tid & 3) * 8;
    ushort* la0 = As + tid * 8;
    ushort* la1 = As + (tid + 256) * 8;
    ushort* lb0 = Bs + tid * 8;
    ushort* lb1 = Bs + (tid + 256) * 8;

    auto stage = [&](int k, int buf) {
        int go = k * 32;
        gload16(Ap0 + go, la0 + buf * ASZ);
        if constexpr (MF == 4) gload16(Ap1 + go, la1 + buf * ASZ);
        gload16(Bp0 + go, lb0 + buf * BSZ);
        if constexpr (NF == 4) gload16(Bp1 + go, lb1 + buf * BSZ);
    };

    constexpr int NK = D / 32;
    stage(0, 0);
    stage(1, 1);

    int cur = 0;
    #pragma unroll 1
    for (int k0 = 0; k0 < NK; ++k0) {
        if (k0 + 1 < NK) waitvm<NL>(); else waitvm<0>();   // own tile-k0 loads done
        rawbar();                                           // collective: tile k0 ready
        int bs = cur + 2; if (bs >= 3) bs -= 3;             // buf of tile k0-1: readers done
        const ushort* Ac = As + cur * ASZ;
        const ushort* Bc = Bs + cur * BSZ;
        bf16x8 af[MF], bfr[NF];
        #pragma unroll
        for (int m = 0; m < MF; ++m) af[m] = *(const bf16x8*)&Ac[(wm + m * 16 + lr) * 32 + lk];
        #pragma unroll
        for (int n = 0; n < NF; ++n) bfr[n] = *(const bf16x8*)&Bc[(wn + n * 16 + lr) * 32 + lk];
        if (k0 + 2 < NK) stage(k0 + 2, bs);                 // fly under MFMA
        __builtin_amdgcn_s_setprio(1);
        #pragma unroll
        for (int m = 0; m < MF; ++m)
            #pragma unroll
            for (int n = 0; n < NF; ++n)
                acc[m][n] = __builtin_amdgcn_mfma_f32_16x16x32_bf16(af[m], bfr[n], acc[m][n], 0, 0, 0);
        __builtin_amdgcn_s_setprio(0);
        cur = (cur == 2) ? 0 : cur + 1;
    }

    if (mode == 0) {
        // (MF=2,NF=4): single-round epilogue — 4 waves cover all 64 rows.
        ushort* E = SH;                 // QK: [64][136]; V: [128][72]
        const bool isV = (blockIdx.y >= 16);
        ushort* DstQK = (blockIdx.y < 8) ? Qd : Kd;
        int bnc = (blockIdx.y & 7) * 128;
        int b = bm >> 11;
        __syncthreads();
        if (!isV) {
            #pragma unroll
            for (int m = 0; m < MF; ++m)
                #pragma unroll
                for (int n = 0; n < NF; ++n)
                    #pragma unroll
                    for (int r = 0; r < 4; ++r)
                        E[(wm + m * 16 + rr + r) * 136 + wn + n * 16 + lr] = f2bf(acc[m][n][r]);
        } else {
            #pragma unroll
            for (int m = 0; m < MF; ++m)
                #pragma unroll
                for (int n = 0; n < NF; ++n) {
                    ushort4 w;
                    w.x = f2bf(acc[m][n][0]); w.y = f2bf(acc[m][n][1]);
                    w.z = f2bf(acc[m][n][2]); w.w = f2bf(acc[m][n][3]);
                    *(ushort4*)&E[(wn + n * 16 + lr) * 72 + wm + m * 16 + rr] = w;
                }
        }
        __syncthreads();
        if (!isV) {
            #pragma unroll
            for (int p = 0; p < 4; ++p) {
                int rloc = (tid >> 4) + p * 16;          // 0..63
                int c8 = (tid & 15) * 8;
                int4 v = *(const int4*)&E[rloc * 136 + c8];
                int gm = bm + rloc;
                int ss = gm & (S - 1);
                int n = bnc + c8;
                int hh = n >> 6, dd = n & 63;
                *(int4*)&DstQK[((size_t)(b * NH + hh) * S + ss) * DH + dd] = v;
            }
        } else {
            #pragma unroll
            for (int p = 0; p < 4; ++p) {
                int c = tid >> 1;                        // 0..127
                int chunk = 2 * p + (tid & 1);           // 0..7
                int4 v = *(const int4*)&E[c * 72 + chunk * 8];
                int n = bnc + c;
                int hh = n >> 6, dd = n & 63;
                int gm = bm + chunk * 8;
                int ss = gm & (S - 1);
                *(int4*)&Vd[((size_t)(b * NH + hh) * DH + dd) * S + ss] = v;
            }
        }
    } else {
        #pragma unroll
        for (int m = 0; m < MF; ++m) {
            #pragma unroll
            for (int n = 0; n < NF; ++n) {
                int gn = bn0 + wn + n * 16 + lr;
                float bv = bias[gn];
                #pragma unroll
                for (int r = 0; r < 4; ++r) {
                    int gm = bm + wm + m * 16 + rr + r;
                    Od[(size_t)gm * D + gn] = acc[m][n][r] + bv;
                }
            }
        }
    }
}

// ---------------- flash attention: R13/R14 structure (best measured) -----------
__global__ __launch_bounds__(256, 4) void k_attn(
    const ushort* __restrict__ Qh, const ushort* __restrict__ Kh,
    const ushort* __restrict__ Vt, ushort* __restrict__ ctx)
{
    __shared__ ushort Ks[2][4096];   // [dbuf][64 kv][64 dh], 16B-chunk XOR swizzled
    __shared__ ushort Vs[2][4096];   // [dbuf][64 dh][64 kv]

    int bid = blockIdx.x;
    int r_ = bid >> 8, c_ = bid & 255;
    int qt = (r_ & 1) ? (c_ >> 3) : 31 - (c_ >> 3);
    int bh = (c_ & 7) + 8 * r_;

    int tid = threadIdx.x;
    int wave = tid >> 6, lane = tid & 63;
    int lo5 = lane & 31, hi = lane >> 5;
    int qs = wave >> 1, kp = wave & 1;
    int rxl = lo5 & 7;
    int b = bh >> 4, h = bh & (NH - 1);

    const ushort* Qp = Qh + (size_t)bh * S * DH;
    const ushort* Kp = Kh + (size_t)bh * S * DH;
    const ushort* Vp = Vt + (size_t)bh * DH * S;

    int q0 = qt * 64, q0w = q0 + qs * 32, qg = q0w + lo5;
    int nt = qt + 1;

    bf16x8 qf[4];
    #pragma unroll
    for (int ks = 0; ks < 4; ++ks)
        qf[ks] = *(const bf16x8*)&Qp[(size_t)qg * DH + ks * 16 + hi * 8];

    int koff[4], vof[2];
    #pragma unroll
    for (int ks = 0; ks < 4; ++ks)
        koff[ks] = (kp * 32 + lo5) * 64 + (((2 * ks + hi) ^ rxl) << 3);
    #pragma unroll
    for (int kc = 0; kc < 2; ++kc)
        vof[kc] = lo5 * 64 + (((kp * 4 + 2 * kc + hi) ^ rxl) << 3);

    int p0 = tid, p1 = tid + 256;
    int kr0 = p0 >> 3, kc0 = ((p0 & 7) ^ (kr0 & 7)) << 3;
    int kr1 = p1 >> 3, kc1 = ((p1 & 7) ^ (kr1 & 7)) << 3;
    const ushort* gkA = Kp + (size_t)kr0 * DH + kc0;
    const ushort* gkB = Kp + (size_t)kr1 * DH + kc1;
    const ushort* gvA = Vp + (size_t)kr0 * S + kc0;
    const ushort* gvB = Vp + (size_t)kr1 * S + kc1;
    ushort* lk0 = &Ks[0][p0 * 8];
    ushort* lk1 = &Ks[0][p1 * 8];
    ushort* lv0 = &Vs[0][p0 * 8];
    ushort* lv1 = &Vs[0][p1 * 8];

    auto stage = [&](int t, int buf) {
        int ko = t * (64 * DH);
        int vo = t * 64;
        int lo = buf * 4096;
        gload16(gkA + ko, lk0 + lo);
        gload16(gkB + ko, lk1 + lo);
        gload16(gvA + vo, lv0 + lo);
        gload16(gvB + vo, lv1 + lo);
    };

    f32x16 oacc[2] = {};
    float l = 0.f;

    stage(0, 0);
    if (nt > 1) stage(1, 1);

    #pragma unroll 1
    for (int t = 0; t < nt; ++t) {
        if (t + 1 < nt) waitvm<4>(); else waitvm<0>();
        rawbar();
        bool fullmask = (t == qt) && (kp == 1) && (qs == 0);
        if (!fullmask) {
            const ushort* KsC = &Ks[t & 1][0];
            const ushort* VsC = &Vs[t & 1][0];
            f32x16 sc = (f32x16)(0.f);
            __builtin_amdgcn_s_setprio(1);
            #pragma unroll
            for (int ks = 0; ks < 4; ++ks) {
                bf16x8 kf = *(const bf16x8*)&KsC[koff[ks]];
                sc = __builtin_amdgcn_mfma_f32_32x32x16_bf16(kf, qf[ks], sc, 0, 0, 0);
            }
            __builtin_amdgcn_s_setprio(0);

            int kv0 = t * 64;
            if (t == qt && !(kp == 0 && qs == 1)) {
                #pragma unroll
                for (int r2 = 0; r2 < 16; ++r2) {
                    int kvg = kv0 + kp * 32 + ((r2 & 3) + 8 * (r2 >> 2) + 4 * hi);
                    sc[r2] = (kvg > qg) ? -1e30f : sc[r2];
                }
            }
            #pragma unroll
            for (int r2 = 0; r2 < 16; ++r2)
                sc[r2] = fexp2(sc[r2]);
            float t0 = sc[0] + sc[1], t1 = sc[2] + sc[3], t2 = sc[4] + sc[5], t3 = sc[6] + sc[7];
            float t4 = sc[8] + sc[9], t5 = sc[10] + sc[11], t6 = sc[12] + sc[13], t7 = sc[14] + sc[15];
            l += ((t0 + t1) + (t2 + t3)) + ((t4 + t5) + (t6 + t7));

            bf16x8 pb[2];
            {
                int a0 = cvtpk_bf16(sc[0], sc[1]);
                int b0 = cvtpk_bf16(sc[4], sc[5]);
                plswap(a0, b0);
                int a1 = cvtpk_bf16(sc[2], sc[3]);
                int b1 = cvtpk_bf16(sc[6], sc[7]);
                plswap(a1, b1);
                int4 w0; w0.x = a0; w0.y = a1; w0.z = b0; w0.w = b1;
                pb[0] = *(bf16x8*)&w0;
                int a2 = cvtpk_bf16(sc[8], sc[9]);
                int b2 = cvtpk_bf16(sc[12], sc[13]);
                plswap(a2, b2);
                int a3 = cvtpk_bf16(sc[10], sc[11]);
                int b3 = cvtpk_bf16(sc[14], sc[15]);
                plswap(a3, b3);
                int4 w1; w1.x = a2; w1.y = a3; w1.z = b2; w1.w = b3;
                pb[1] = *(bf16x8*)&w1;
            }

            __builtin_amdgcn_s_setprio(1);
            #pragma unroll
            for (int kc = 0; kc < 2; ++kc) {
                bf16x8 vf0 = *(const bf16x8*)&VsC[vof[kc]];
                oacc[0] = __builtin_amdgcn_mfma_f32_32x32x16_bf16(vf0, pb[kc], oacc[0], 0, 0, 0);
                bf16x8 vf1 = *(const bf16x8*)&VsC[vof[kc] + 32 * 64];
                oacc[1] = __builtin_amdgcn_mfma_f32_32x32x16_bf16(vf1, pb[kc], oacc[1], 0, 0, 0);
            }
            __builtin_amdgcn_s_setprio(0);
        }
        waitlgkm0();
        rawbar();
        if (t + 2 < nt) stage(t + 2, t & 1);
    }

    l = xhalf_add(l);

    float4* scr4 = (float4*)&Ks[0][0];
    float* ls = (float*)&Vs[0][0];
    int row = qs * 64 + lane;
    if (kp == 1) {
        #pragma unroll
        for (int sub = 0; sub < 2; ++sub)
            #pragma unroll
            for (int cc = 0; cc < 4; ++cc) {
                float4 v4;
                v4.x = oacc[sub][4 * cc + 0];
                v4.y = oacc[sub][4 * cc + 1];
                v4.z = oacc[sub][4 * cc + 2];
                v4.w = oacc[sub][4 * cc + 3];
                scr4[row * 8 + ((sub * 4 + cc) ^ (row & 7))] = v4;
            }
        ls[row] = l;
    }
    __syncthreads();
    if (kp == 0) {
        float inv = 1.0f / (l + ls[row]);
        ushort* cp = ctx + (size_t)(b * S + qg) * D + h * DH;
        #pragma unroll
        for (int sub = 0; sub < 2; ++sub) {
            #pragma unroll
            for (int cc = 0; cc < 4; ++cc) {
                float4 v4 = scr4[row * 8 + ((sub * 4 + cc) ^ (row & 7))];
                float o0 = (oacc[sub][4 * cc + 0] + v4.x) * inv;
                float o1 = (oacc[sub][4 * cc + 1] + v4.y) * inv;
                float o2 = (oacc[sub][4 * cc + 2] + v4.z) * inv;
                float o3 = (oacc[sub][4 * cc + 3] + v4.w) * inv;
                int dh = 8 * cc + 4 * hi + 32 * sub;
                int2 w2; w2.x = cvtpk_bf16(o0, o1); w2.y = cvtpk_bf16(o2, o3);
                *(int2*)&cp[dh] = w2;
            }
        }
    }
}

extern "C" void kernel_launch(void* const* d_in, const int* in_sizes, int n_in,
                              void* d_out, int out_size, void* d_ws, size_t ws_size,
                              hipStream_t stream) {
    const float* X   = (const float*)d_in[0];
    const float* W_q = (const float*)d_in[1];
    const float* W_k = (const float*)d_in[2];
    const float* W_v = (const float*)d_in[3];
    const float* W_o = (const float*)d_in[4];
    const float* b_o = (const float*)d_in[5];
    float* out = (float*)d_out;

    ushort* Xb    = (ushort*)d_ws;
    ushort* Wqkvt = Xb    + (size_t)M_TOT * D;
    ushort* Wot   = Wqkvt + (size_t)3 * D * D;
    ushort* Qh    = Wot   + (size_t)D * D;
    ushort* Kh    = Qh    + (size_t)M_TOT * D;
    ushort* Vtr   = Kh    + (size_t)M_TOT * D;   // [32][64][2048], written by k_gemm mode 0
    ushort* Ctx   = Vtr   + (size_t)M_TOT * D;

    k_prep<<<dim3(32, 32, 8), dim3(256), 0, stream>>>(
        X, W_q, W_k, W_v, W_o, Xb, Wqkvt, Wot, 0.18033688011112042f);

    // QKV: BM=64 -> 1536 blocks = 6/CU (4 resident at 36KB LDS)
    k_gemm<2, 4><<<dim3(64, 24), dim3(256), 0, stream>>>(Xb, Wqkvt, Qh, Kh, Vtr, nullptr, nullptr, 0);

    k_attn<<<dim3(1024), dim3(256), 0, stream>>>(Qh, Kh, Vtr, Ctx);

    // out-proj: BM=64, BN=64 -> 1024 blocks = 4/CU
    k_gemm<2, 2><<<dim3(64, 16), dim3(256), 0, stream>>>(Ctx, Wot, nullptr, nullptr, nullptr, out, b_o, 1);
}

// Round 17
// 100.703 us; speedup vs baseline: 1.1036x; 1.1036x over previous
//
#include <hip/hip_runtime.h>
#include <hip/hip_bf16.h>

#define S 2048
#define D 1024
#define NH 16
#define DH 64
#define M_TOT 4096  // B*S

typedef float f32x4 __attribute__((ext_vector_type(4)));
typedef float f32x16 __attribute__((ext_vector_type(16)));
typedef __bf16 bf16x8 __attribute__((ext_vector_type(8)));

static __device__ __forceinline__ ushort f2bf(float f) {
    unsigned u = __float_as_uint(f);
    u += 0x7fffu + ((u >> 16) & 1u);   // RNE
    return (ushort)(u >> 16);
}

static __device__ __forceinline__ int cvtpk_bf16(float lo, float hi) {
    int r;
    asm("v_cvt_pk_bf16_f32 %0, %1, %2" : "=v"(r) : "v"(lo), "v"(hi));
    return r;
}

static __device__ __forceinline__ void plswap(int& a, int& b) {
    asm("v_permlane32_swap_b32 %0, %1" : "+v"(a), "+v"(b));
}

static __device__ __forceinline__ float xhalf_add(float x) {
    return x + __shfl_xor(x, 32);
}

// bare hardware exp2 (skips __ocml_exp2_f32's denormal fixup)
static __device__ __forceinline__ float fexp2(float x) {
    float r;
    asm("v_exp_f32 %0, %1" : "=v"(r) : "v"(x));
    return r;
}

static __device__ __forceinline__ void gload16(const ushort* g, ushort* l) {
    __builtin_amdgcn_global_load_lds(
        (const __attribute__((address_space(1))) void*)g,
        (__attribute__((address_space(3))) void*)l, 16, 0, 0);
}

// counted vmcnt wait (T4)
template<int N> static __device__ __forceinline__ void waitvm() {
    if constexpr (N == 0) asm volatile("s_waitcnt vmcnt(0)" ::: "memory");
    else if constexpr (N == 3) asm volatile("s_waitcnt vmcnt(3)" ::: "memory");
    else if constexpr (N == 4) asm volatile("s_waitcnt vmcnt(4)" ::: "memory");
}
static __device__ __forceinline__ void waitlgkm0() {
    asm volatile("s_waitcnt lgkmcnt(0)" ::: "memory");
}
static __device__ __forceinline__ void rawbar() {
    __builtin_amdgcn_s_barrier();
    __builtin_amdgcn_sched_barrier(0);
}

// ---------------- fused prep: X->bf16 convert + all weight transposes ----------
__global__ void k_prep(const float* __restrict__ X, const float* __restrict__ Wq,
                       const float* __restrict__ Wk, const float* __restrict__ Wv,
                       const float* __restrict__ Wo,
                       ushort* __restrict__ Xb, ushort* __restrict__ Wqkvt,
                       ushort* __restrict__ Wot, float scale0) {
    int z = blockIdx.z;
    int tid = threadIdx.x;
    if (z >= 4) {
        int idx = (((z - 4) * 1024) + blockIdx.y * 32 + blockIdx.x) * 256 + tid;
        float4 v = ((const float4*)X)[idx];
        ushort4 o;
        o.x = f2bf(v.x); o.y = f2bf(v.y); o.z = f2bf(v.z); o.w = f2bf(v.w);
        ((ushort4*)Xb)[idx] = o;
        return;
    }
    __shared__ float tile[32][33];
    const float* src = (z == 0) ? Wq : (z == 1) ? Wk : (z == 2) ? Wv : Wo;
    ushort* dst = (z < 3) ? (Wqkvt + (size_t)z * 1024 * D) : Wot;
    float scl = (z == 0) ? scale0 : 1.0f;
    int bn = blockIdx.x * 32;
    int bk = blockIdx.y * 32;
    int tx = tid & 31, ty = tid >> 5;
    #pragma unroll
    for (int i = 0; i < 32; i += 8)
        tile[ty + i][tx] = src[(size_t)(bk + ty + i) * D + bn + tx];
    __syncthreads();
    #pragma unroll
    for (int i = 0; i < 32; i += 8)
        dst[(size_t)(bn + ty + i) * D + bk + tx] = f2bf(tile[tx][ty + i] * scl);
}

// ---------------- GEMM TN, 3-buffer / 1-barrier counted-vmcnt pipeline ----------
template<int MF>
__global__ __launch_bounds__(256) void k_gemm(
    const ushort* __restrict__ A, const ushort* __restrict__ Bt,
    ushort* __restrict__ Qd, ushort* __restrict__ Kd, ushort* __restrict__ Vd,
    float* __restrict__ Od, const float* __restrict__ bias, int mode)
{
    constexpr int BM = MF * 32;
    constexpr int ASZ = BM * 32;
    constexpr int BSZ = 128 * 32;
    constexpr int NL = (MF == 4) ? 4 : 3;     // loads per stage (left in flight)
    __shared__ ushort SH[3 * ASZ + 3 * BSZ];
    ushort* As = SH;
    ushort* Bs = SH + 3 * ASZ;

    int tid = threadIdx.x, wave = tid >> 6, lane = tid & 63;
    int wm = (wave >> 1) * (MF * 16), wn = (wave & 1) * 64;
    int bm = blockIdx.x * BM, bn0 = blockIdx.y * 128;
    int lr = lane & 15, lk = (lane >> 4) * 8;
    int rr = (lane >> 4) * 4;
    f32x4 acc[MF][4] = {};

    const ushort* Ap0 = A + (size_t)(bm + (tid >> 2)) * D + (tid & 3) * 8;
    const ushort* Ap1 = A + (size_t)(bm + ((tid + 256) >> 2)) * D + (tid & 3) * 8;
    const ushort* Bp0 = Bt + (size_t)(bn0 + (tid >> 2)) * D + (tid & 3) * 8;
    const ushort* Bp1 = Bt + (size_t)(bn0 + ((tid + 256) >> 2)) * D + (tid & 3) * 8;
    ushort* la0 = As + tid * 8;
    ushort* la1 = As + (tid + 256) * 8;
    ushort* lb0 = Bs + tid * 8;
    ushort* lb1 = Bs + (tid + 256) * 8;

    auto stage = [&](int k, int buf) {
        int go = k * 32;
        gload16(Ap0 + go, la0 + buf * ASZ);
        if constexpr (MF == 4) gload16(Ap1 + go, la1 + buf * ASZ);
        gload16(Bp0 + go, lb0 + buf * BSZ);
        gload16(Bp1 + go, lb1 + buf * BSZ);
    };

    constexpr int NK = D / 32;
    stage(0, 0);
    stage(1, 1);

    int cur = 0;
    #pragma unroll 1
    for (int k0 = 0; k0 < NK; ++k0) {
        if (k0 + 1 < NK) waitvm<NL>(); else waitvm<0>();   // own tile-k0 loads done
        rawbar();                                           // collective: tile k0 ready
        int bs = cur + 2; if (bs >= 3) bs -= 3;             // buf of tile k0-1: readers done
        const ushort* Ac = As + cur * ASZ;
        const ushort* Bc = Bs + cur * BSZ;
        bf16x8 af[MF], bfr[4];
        #pragma unroll
        for (int m = 0; m < MF; ++m) af[m] = *(const bf16x8*)&Ac[(wm + m * 16 + lr) * 32 + lk];
        #pragma unroll
        for (int n = 0; n < 4; ++n) bfr[n] = *(const bf16x8*)&Bc[(wn + n * 16 + lr) * 32 + lk];
        if (k0 + 2 < NK) stage(k0 + 2, bs);                 // fly under MFMA
        __builtin_amdgcn_s_setprio(1);
        #pragma unroll
        for (int m = 0; m < MF; ++m)
            #pragma unroll
            for (int n = 0; n < 4; ++n)
                acc[m][n] = __builtin_amdgcn_mfma_f32_16x16x32_bf16(af[m], bfr[n], acc[m][n], 0, 0, 0);
        __builtin_amdgcn_s_setprio(0);
        cur = (cur == 2) ? 0 : cur + 1;
    }

    if (mode == 0) {
        ushort* E = SH;
        const bool isV = (blockIdx.y >= 16);
        ushort* DstQK = (blockIdx.y < 8) ? Qd : Kd;
        int bnc = (blockIdx.y & 7) * 128;
        int b = bm >> 11;
        #pragma unroll 1
        for (int hh2 = 0; hh2 < 2; ++hh2) {
            __syncthreads();
            if (wm == hh2 * 64) {
                if (!isV) {
                    #pragma unroll
                    for (int m = 0; m < MF; ++m)
                        #pragma unroll
                        for (int n = 0; n < 4; ++n)
                            #pragma unroll
                            for (int r = 0; r < 4; ++r)
                                E[(m * 16 + rr + r) * 136 + wn + n * 16 + lr] = f2bf(acc[m][n][r]);
                } else {
                    #pragma unroll
                    for (int m = 0; m < MF; ++m)
                        #pragma unroll
                        for (int n = 0; n < 4; ++n) {
                            ushort4 w;
                            w.x = f2bf(acc[m][n][0]); w.y = f2bf(acc[m][n][1]);
                            w.z = f2bf(acc[m][n][2]); w.w = f2bf(acc[m][n][3]);
                            *(ushort4*)&E[(wn + n * 16 + lr) * 72 + m * 16 + rr] = w;
                        }
                }
            }
            __syncthreads();
            if (!isV) {
                #pragma unroll
                for (int p = 0; p < 4; ++p) {
                    int rloc = (tid >> 4) + p * 16;
                    int c8 = (tid & 15) * 8;
                    int4 v = *(const int4*)&E[rloc * 136 + c8];
                    int gm = bm + hh2 * 64 + rloc;
                    int ss = gm & (S - 1);
                    int n = bnc + c8;
                    int hh = n >> 6, dd = n & 63;
                    *(int4*)&DstQK[((size_t)(b * NH + hh) * S + ss) * DH + dd] = v;
                }
            } else {
                #pragma unroll
                for (int p = 0; p < 4; ++p) {
                    int c = tid >> 1;
                    int chunk = 2 * p + (tid & 1);
                    int4 v = *(const int4*)&E[c * 72 + chunk * 8];
                    int n = bnc + c;
                    int hh = n >> 6, dd = n & 63;
                    int gm = bm + hh2 * 64 + chunk * 8;
                    int ss = gm & (S - 1);
                    *(int4*)&Vd[((size_t)(b * NH + hh) * DH + dd) * S + ss] = v;
                }
            }
        }
    } else {
        #pragma unroll
        for (int m = 0; m < MF; ++m) {
            #pragma unroll
            for (int n = 0; n < 4; ++n) {
                int gn = bn0 + wn + n * 16 + lr;
                float bv = bias[gn];
                #pragma unroll
                for (int r = 0; r < 4; ++r) {
                    int gm = bm + wm + m * 16 + rr + r;
                    Od[(size_t)gm * D + gn] = acc[m][n][r] + bv;
                }
            }
        }
    }
}

// ---------------- flash attention: R13/R14 structure (best measured) -----------
__global__ __launch_bounds__(256, 4) void k_attn(
    const ushort* __restrict__ Qh, const ushort* __restrict__ Kh,
    const ushort* __restrict__ Vt, ushort* __restrict__ ctx)
{
    __shared__ ushort Ks[2][4096];   // [dbuf][64 kv][64 dh], 16B-chunk XOR swizzled
    __shared__ ushort Vs[2][4096];   // [dbuf][64 dh][64 kv]

    int bid = blockIdx.x;
    int r_ = bid >> 8, c_ = bid & 255;
    int qt = (r_ & 1) ? (c_ >> 3) : 31 - (c_ >> 3);
    int bh = (c_ & 7) + 8 * r_;

    int tid = threadIdx.x;
    int wave = tid >> 6, lane = tid & 63;
    int lo5 = lane & 31, hi = lane >> 5;
    int qs = wave >> 1, kp = wave & 1;
    int rxl = lo5 & 7;
    int b = bh >> 4, h = bh & (NH - 1);

    const ushort* Qp = Qh + (size_t)bh * S * DH;
    const ushort* Kp = Kh + (size_t)bh * S * DH;
    const ushort* Vp = Vt + (size_t)bh * DH * S;

    int q0 = qt * 64, q0w = q0 + qs * 32, qg = q0w + lo5;
    int nt = qt + 1;

    bf16x8 qf[4];
    #pragma unroll
    for (int ks = 0; ks < 4; ++ks)
        qf[ks] = *(const bf16x8*)&Qp[(size_t)qg * DH + ks * 16 + hi * 8];

    int koff[4], vof[2];
    #pragma unroll
    for (int ks = 0; ks < 4; ++ks)
        koff[ks] = (kp * 32 + lo5) * 64 + (((2 * ks + hi) ^ rxl) << 3);
    #pragma unroll
    for (int kc = 0; kc < 2; ++kc)
        vof[kc] = lo5 * 64 + (((kp * 4 + 2 * kc + hi) ^ rxl) << 3);

    int p0 = tid, p1 = tid + 256;
    int kr0 = p0 >> 3, kc0 = ((p0 & 7) ^ (kr0 & 7)) << 3;
    int kr1 = p1 >> 3, kc1 = ((p1 & 7) ^ (kr1 & 7)) << 3;
    const ushort* gkA = Kp + (size_t)kr0 * DH + kc0;
    const ushort* gkB = Kp + (size_t)kr1 * DH + kc1;
    const ushort* gvA = Vp + (size_t)kr0 * S + kc0;
    const ushort* gvB = Vp + (size_t)kr1 * S + kc1;
    ushort* lk0 = &Ks[0][p0 * 8];
    ushort* lk1 = &Ks[0][p1 * 8];
    ushort* lv0 = &Vs[0][p0 * 8];
    ushort* lv1 = &Vs[0][p1 * 8];

    auto stage = [&](int t, int buf) {
        int ko = t * (64 * DH);
        int vo = t * 64;
        int lo = buf * 4096;
        gload16(gkA + ko, lk0 + lo);
        gload16(gkB + ko, lk1 + lo);
        gload16(gvA + vo, lv0 + lo);
        gload16(gvB + vo, lv1 + lo);
    };

    f32x16 oacc[2] = {};
    float l = 0.f;

    stage(0, 0);
    if (nt > 1) stage(1, 1);

    #pragma unroll 1
    for (int t = 0; t < nt; ++t) {
        if (t + 1 < nt) waitvm<4>(); else waitvm<0>();
        rawbar();
        bool fullmask = (t == qt) && (kp == 1) && (qs == 0);
        if (!fullmask) {
            const ushort* KsC = &Ks[t & 1][0];
            const ushort* VsC = &Vs[t & 1][0];
            f32x16 sc = (f32x16)(0.f);
            __builtin_amdgcn_s_setprio(1);
            #pragma unroll
            for (int ks = 0; ks < 4; ++ks) {
                bf16x8 kf = *(const bf16x8*)&KsC[koff[ks]];
                sc = __builtin_amdgcn_mfma_f32_32x32x16_bf16(kf, qf[ks], sc, 0, 0, 0);
            }
            __builtin_amdgcn_s_setprio(0);

            int kv0 = t * 64;
            if (t == qt && !(kp == 0 && qs == 1)) {
                #pragma unroll
                for (int r2 = 0; r2 < 16; ++r2) {
                    int kvg = kv0 + kp * 32 + ((r2 & 3) + 8 * (r2 >> 2) + 4 * hi);
                    sc[r2] = (kvg > qg) ? -1e30f : sc[r2];
                }
            }
            #pragma unroll
            for (int r2 = 0; r2 < 16; ++r2)
                sc[r2] = fexp2(sc[r2]);
            float t0 = sc[0] + sc[1], t1 = sc[2] + sc[3], t2 = sc[4] + sc[5], t3 = sc[6] + sc[7];
            float t4 = sc[8] + sc[9], t5 = sc[10] + sc[11], t6 = sc[12] + sc[13], t7 = sc[14] + sc[15];
            l += ((t0 + t1) + (t2 + t3)) + ((t4 + t5) + (t6 + t7));

            bf16x8 pb[2];
            {
                int a0 = cvtpk_bf16(sc[0], sc[1]);
                int b0 = cvtpk_bf16(sc[4], sc[5]);
                plswap(a0, b0);
                int a1 = cvtpk_bf16(sc[2], sc[3]);
                int b1 = cvtpk_bf16(sc[6], sc[7]);
                plswap(a1, b1);
                int4 w0; w0.x = a0; w0.y = a1; w0.z = b0; w0.w = b1;
                pb[0] = *(bf16x8*)&w0;
                int a2 = cvtpk_bf16(sc[8], sc[9]);
                int b2 = cvtpk_bf16(sc[12], sc[13]);
                plswap(a2, b2);
                int a3 = cvtpk_bf16(sc[10], sc[11]);
                int b3 = cvtpk_bf16(sc[14], sc[15]);
                plswap(a3, b3);
                int4 w1; w1.x = a2; w1.y = a3; w1.z = b2; w1.w = b3;
                pb[1] = *(bf16x8*)&w1;
            }

            __builtin_amdgcn_s_setprio(1);
            #pragma unroll
            for (int kc = 0; kc < 2; ++kc) {
                bf16x8 vf0 = *(const bf16x8*)&VsC[vof[kc]];
                oacc[0] = __builtin_amdgcn_mfma_f32_32x32x16_bf16(vf0, pb[kc], oacc[0], 0, 0, 0);
                bf16x8 vf1 = *(const bf16x8*)&VsC[vof[kc] + 32 * 64];
                oacc[1] = __builtin_amdgcn_mfma_f32_32x32x16_bf16(vf1, pb[kc], oacc[1], 0, 0, 0);
            }
            __builtin_amdgcn_s_setprio(0);
        }
        waitlgkm0();
        rawbar();
        if (t + 2 < nt) stage(t + 2, t & 1);
    }

    l = xhalf_add(l);

    float4* scr4 = (float4*)&Ks[0][0];
    float* ls = (float*)&Vs[0][0];
    int row = qs * 64 + lane;
    if (kp == 1) {
        #pragma unroll
        for (int sub = 0; sub < 2; ++sub)
            #pragma unroll
            for (int cc = 0; cc < 4; ++cc) {
                float4 v4;
                v4.x = oacc[sub][4 * cc + 0];
                v4.y = oacc[sub][4 * cc + 1];
                v4.z = oacc[sub][4 * cc + 2];
                v4.w = oacc[sub][4 * cc + 3];
                scr4[row * 8 + ((sub * 4 + cc) ^ (row & 7))] = v4;
            }
        ls[row] = l;
    }
    __syncthreads();
    if (kp == 0) {
        float inv = 1.0f / (l + ls[row]);
        ushort* cp = ctx + (size_t)(b * S + qg) * D + h * DH;
        #pragma unroll
        for (int sub = 0; sub < 2; ++sub) {
            #pragma unroll
            for (int cc = 0; cc < 4; ++cc) {
                float4 v4 = scr4[row * 8 + ((sub * 4 + cc) ^ (row & 7))];
                float o0 = (oacc[sub][4 * cc + 0] + v4.x) * inv;
                float o1 = (oacc[sub][4 * cc + 1] + v4.y) * inv;
                float o2 = (oacc[sub][4 * cc + 2] + v4.z) * inv;
                float o3 = (oacc[sub][4 * cc + 3] + v4.w) * inv;
                int dh = 8 * cc + 4 * hi + 32 * sub;
                int2 w2; w2.x = cvtpk_bf16(o0, o1); w2.y = cvtpk_bf16(o2, o3);
                *(int2*)&cp[dh] = w2;
            }
        }
    }
}

extern "C" void kernel_launch(void* const* d_in, const int* in_sizes, int n_in,
                              void* d_out, int out_size, void* d_ws, size_t ws_size,
                              hipStream_t stream) {
    const float* X   = (const float*)d_in[0];
    const float* W_q = (const float*)d_in[1];
    const float* W_k = (const float*)d_in[2];
    const float* W_v = (const float*)d_in[3];
    const float* W_o = (const float*)d_in[4];
    const float* b_o = (const float*)d_in[5];
    float* out = (float*)d_out;

    ushort* Xb    = (ushort*)d_ws;
    ushort* Wqkvt = Xb    + (size_t)M_TOT * D;
    ushort* Wot   = Wqkvt + (size_t)3 * D * D;
    ushort* Qh    = Wot   + (size_t)D * D;
    ushort* Kh    = Qh    + (size_t)M_TOT * D;
    ushort* Vtr   = Kh    + (size_t)M_TOT * D;   // [32][64][2048], written by k_gemm<4>
    ushort* Ctx   = Vtr   + (size_t)M_TOT * D;

    // fused prep: convert X + transpose all weights (softmax scale folded into W_q)
    k_prep<<<dim3(32, 32, 8), dim3(256), 0, stream>>>(
        X, W_q, W_k, W_v, W_o, Xb, Wqkvt, Wot, 0.18033688011112042f);

    k_gemm<4><<<dim3(32, 24), dim3(256), 0, stream>>>(Xb, Wqkvt, Qh, Kh, Vtr, nullptr, nullptr, 0);

    k_attn<<<dim3(1024), dim3(256), 0, stream>>>(Qh, Kh, Vtr, Ctx);

    k_gemm<2><<<dim3(64, 8), dim3(256), 0, stream>>>(Ctx, Wot, nullptr, nullptr, nullptr, out, b_o, 1);
}